// Round 14
// baseline (1053.692 us; speedup 1.0000x reference)
//
#include <hip/hip_runtime.h>

// DST-I spectral Helmholtz solver, NZ=4, NX=NY=2048.
// Even/odd mirror-fold (half FLOPs); B from transposed tables (L3-hot);
// GEMM: 256x256 tile, BK=32, 64KB dbuf LDS -> 2 blocks/CU (cross-block stall
// hiding), pair-group swizzle, compiler-scheduled interior, 1 barrier/K-tile;
// two-pass LDS-staged coalesced C writes; G2 computes H in-epilogue.

typedef __attribute__((ext_vector_type(8))) short bf16x8;
typedef __attribute__((ext_vector_type(4))) float f32x4;
typedef __attribute__((ext_vector_type(8))) unsigned short ushort8;

#define LDS_SPACE __attribute__((address_space(3)))
#define GLB_SPACE __attribute__((address_space(1)))

__device__ __forceinline__ void gld_lds16(const unsigned short* g, unsigned short* l) {
  __builtin_amdgcn_global_load_lds((const GLB_SPACE void*)g, (LDS_SPACE void*)l, 16, 0, 0);
}

__device__ __forceinline__ float sinrev(float rev) {   // sin(2*pi*rev), exact arg
  float r;
  asm("v_sin_f32 %0, %1" : "=v"(r) : "v"(rev));
  return r;
}

__device__ __forceinline__ unsigned short f2b(float f) {
  union { float f; unsigned u; } v; v.f = f;
  unsigned r = (v.u + 0x7fffu + ((v.u >> 16) & 1u)) >> 16;  // RNE
  return (unsigned short)r;
}
__device__ __forceinline__ float b2f(unsigned short u) {
  union { unsigned u; float f; } v; v.u = ((unsigned)u) << 16;
  return v.f;
}

// ---- tables: T[tbl][n][k] (transposed), bf16.  0:TE1 1:TO1 2:TE3 3:TO3 ----
__global__ __launch_bounds__(256)
void tables_kernel(unsigned short* __restrict__ T) {
  const int idx = blockIdx.x * 256 + threadIdx.x;     // < 4*1024*1024
  const int tbl = idx >> 20, n = (idx >> 10) & 1023, k = idx & 1023;
  int a;
  if (tbl < 2) a = k;                                  // natural pair-rep order
  else a = (k < 512) ? 2 * k : (k < 1023 ? 2 * (k - 512) + 1 : 1023);
  const int cp1 = (tbl & 1) ? 2 * n + 2 : 2 * n + 1;   // j_true+1
  const int ph = ((a + 1) * cp1) & 4095;               // exact phase mod 2*pi
  const float v = 0.03125f * sinrev((float)ph * (1.0f / 4096.0f));
  T[idx] = f2b(v);
}

// ---- mix + natural fold along y: AE/AO [4*2048 x 1024] bf16 ----
__global__ __launch_bounds__(256)
void mix_fold(const float* __restrict__ q, const float* __restrict__ Cl2m,
              unsigned short* __restrict__ AE, unsigned short* __restrict__ AO) {
  const int idx = blockIdx.x * 256 + threadIdx.x;     // < 2048*1024
  const int x = idx >> 10, u = idx & 1023;
  float c[16];
#pragma unroll
  for (int i = 0; i < 16; ++i) c[i] = Cl2m[i];
  float fe[4] = {0.f, 0.f, 0.f, 0.f}, fo[4] = {0.f, 0.f, 0.f, 0.f};
  if (x < 2047) {
#pragma unroll
    for (int l = 0; l < 4; ++l) {
      const size_t base = ((size_t)l * 2047 + x) * 2047;
      const float qa = q[base + u];
      const float qb = (u < 1023) ? q[base + 2046 - u] : 0.f;
      const float E = (u == 1023) ? qa : qa + qb;
      const float O = (u == 1023) ? 0.f : qa - qb;
#pragma unroll
      for (int m = 0; m < 4; ++m) { fe[m] += c[m * 4 + l] * E; fo[m] += c[m * 4 + l] * O; }
    }
  }
#pragma unroll
  for (int m = 0; m < 4; ++m) {
    AE[((size_t)m * 2048 + x) * 1024 + u] = f2b(fe[m]);
    AO[((size_t)m * 2048 + x) * 1024 + u] = f2b(fo[m]);
  }
}

// ---- transpose + fold (per mode): out[c][u] = in[r1(u)][c] +/- in[r2(u)][c] ----
template <int MAP>
__global__ __launch_bounds__(256)
void tfold(const unsigned short* __restrict__ in, unsigned short* __restrict__ outE,
           unsigned short* __restrict__ outO) {
  __shared__ unsigned short t1[64][72];
  __shared__ unsigned short t2[64][72];
  const size_t ib = (size_t)blockIdx.z * (2048u * 2048u);
  const size_t ob = (size_t)blockIdx.z * (2048u * 1024u);
  const int c0 = blockIdx.x * 64, u0 = blockIdx.y * 64;
  const int t = threadIdx.x;
  const int rr = t >> 3, cc = (t & 7) * 8;
#pragma unroll
  for (int ch = 0; ch < 2; ++ch) {
    const int r = ch * 32 + rr, u = u0 + r;
    const int r1 = (MAP == 0) ? u : (u < 512 ? u : 1024 + (u - 512));
    const int r2 = (MAP == 0) ? 2046 - u : (u < 512 ? 1023 - u : 2046 - (u - 512));
    ushort8 v1 = *(const ushort8*)&in[ib + (size_t)r1 * 2048 + c0 + cc];
    ushort8 v2 = *(const ushort8*)&in[ib + (size_t)r2 * 2048 + c0 + cc];
#pragma unroll
    for (int j = 0; j < 8; ++j) { t1[r][cc + j] = v1[j]; t2[r][cc + j] = v2[j]; }
  }
  __syncthreads();
#pragma unroll
  for (int ch = 0; ch < 2; ++ch) {
    const int r = ch * 32 + rr;
    ushort8 vE, vO;
#pragma unroll
    for (int j = 0; j < 8; ++j) {
      const int uu = u0 + cc + j;
      const float a = b2f(t1[cc + j][r]);
      const float b = b2f(t2[cc + j][r]);
      vE[j] = f2b((uu == 1023) ? a : a + b);
      vO[j] = f2b((uu == 1023) ? 0.f : a - b);
    }
    const size_t o = ob + (size_t)(c0 + r) * 1024 + u0 + cc;
    *(ushort8*)&outE[o] = vE;
    *(ushort8*)&outO[o] = vO;
  }
}

// ---- column fold over interleaved axis (no transpose): pre-G3 ----
__global__ __launch_bounds__(256)
void fold_cols(const unsigned short* __restrict__ R, unsigned short* __restrict__ AE,
               unsigned short* __restrict__ AO) {
  const int idx = blockIdx.x * 256 + threadIdx.x;     // < 8192*1024
  const int row = idx >> 10, u = idx & 1023;
  const int c1 = (u < 512) ? u : (u < 1023 ? 512 + u : 1535);
  const int c2 = (u < 512) ? 1023 - u : (u < 1023 ? 2558 - u : 1535);
  const float a = b2f(R[(size_t)row * 2048 + c1]);
  const float b = b2f(R[(size_t)row * 2048 + c2]);
  AE[(size_t)row * 1024 + u] = f2b((u == 1023) ? a : a + b);
  AO[(size_t)row * 1024 + u] = f2b((u == 1023) ? 0.f : a - b);
}

// ---- GEMM: C_half[8192x1024] = A_half[8192x1024] * T_half^T ----
// 256x256 tile, BK=32, 8 waves (2Mx4N), 64KB LDS dbuf -> 2 blocks/CU.
// EPI 0: plain. EPI 1: divide by H computed in-epilogue. EPI 2: + per-mode sum.
#define MFMA_BF16 __builtin_amdgcn_mfma_f32_16x16x32_bf16

template <int EPI>
__global__ __launch_bounds__(512, 4)
void gemm_eo(const unsigned short* __restrict__ A, const unsigned short* __restrict__ T,
             unsigned short* __restrict__ Cb, const float* __restrict__ H,
             float* __restrict__ sums) {
  __shared__ __align__(16) char lds[65536];  // 2 x (A 16KB + B 16KB); epi: 128x256 C halves
  const int bid = blockIdx.x;
  const int swz = (bid & 7) * 32 + (bid >> 3);      // XCD-bijective (256 % 8 == 0)
  const int h = swz & 1;                            // 0: even(E), 1: odd(O)
  const int bn = (swz >> 1) & 3, bm = swz >> 3;
  const int tid = threadIdx.x;
  const int lane = tid & 63, wave = tid >> 6;
  const int wr = wave >> 2, wc = wave & 3;          // 2(M) x 4(N) wave grid
  const int lr = lane & 15, kg = lane >> 4;         // kg = k16 slot (BK=32 -> 4 slots)

  const unsigned short* gA = A + (size_t)h * 8388608u + (size_t)bm * 256 * 1024;
  const unsigned short* gB = T + (size_t)h * 1048576u + (size_t)bn * 256 * 1024;

  // pair-group swizzle (rows have 4 x 16B slots): physical slot ps ->
  // pg=ps>>3, p=(ps&7)^(pg&7); row=2*pg+(p>>2); k16=p&3.  byte = pg*128+(ps&7)*16.
  auto stage = [&](int kt, int c) {
    char* lcA = lds + c * 32768;
    char* lcB = lcA + 16384;
#pragma unroll
    for (int i = 0; i < 2; ++i) {                    // A: 1024 slots (256 rows x 64B)
      const int ps = tid + i * 512;
      const int pg = ps >> 3, p = (ps & 7) ^ (pg & 7);
      const int row = 2 * pg + (p >> 2), k16 = p & 3;
      gld_lds16(gA + (size_t)row * 1024 + kt * 32 + k16 * 8,
                (unsigned short*)(lcA + ps * 16));
    }
#pragma unroll
    for (int i = 0; i < 2; ++i) {                    // B: 1024 slots
      const int ps = tid + i * 512;
      const int pg = ps >> 3, p = (ps & 7) ^ (pg & 7);
      const int row = 2 * pg + (p >> 2), k16 = p & 3;
      gld_lds16(gB + (size_t)row * 1024 + kt * 32 + k16 * 8,
                (unsigned short*)(lcB + ps * 16));
    }
  };

  f32x4 acc[8][4];
#pragma unroll
  for (int m = 0; m < 8; ++m)
#pragma unroll
    for (int n = 0; n < 4; ++n) acc[m][n] = (f32x4){0.f, 0.f, 0.f, 0.f};

  stage(0, 0);
  stage(1, 1);
  __syncthreads();

  const LDS_SPACE char* lbase = (const LDS_SPACE char*)lds;

  // read byte for (row, kg): (row>>1)*128 + ((((row&1)<<2)|kg) ^ ((row>>1)&7))*16
  auto rdoff = [&](int row) {
    return (row >> 1) * 128 + (((((row & 1) << 2) | kg) ^ ((row >> 1) & 7)) << 4);
  };

  for (int t = 0; t < 32; ++t) {
    const LDS_SPACE char* la = lbase + (t & 1) * 32768;
    const LDS_SPACE char* lb = la + 16384;

    bf16x8 av[8], bv[4];
#pragma unroll
    for (int m = 0; m < 8; ++m)
      av[m] = *(const LDS_SPACE bf16x8*)(la + rdoff(wr * 128 + m * 16 + lr));
#pragma unroll
    for (int n = 0; n < 4; ++n)
      bv[n] = *(const LDS_SPACE bf16x8*)(lb + rdoff(wc * 64 + n * 16 + lr));

#pragma unroll
    for (int m = 0; m < 8; ++m)
#pragma unroll
      for (int n = 0; n < 4; ++n)
        acc[m][n] = MFMA_BF16(av[m], bv[n], acc[m][n], 0, 0, 0);

    // one barrier per K-tile: all waves done reading buf[t&1]; staging issued
    // last iteration has drained (syncthreads waits vmcnt(0)) and is published.
    __syncthreads();
    if (t < 30) stage(t + 2, t & 1);
  }

  // ---- EPI1 constants: H(a,b) = t(a+1)+t(b+1)-beta, t(x) = -2.5e-7*sin^2(pi*x/4096)
  float beta = 0.f, tA[4];
  bool iok[4] = {true, true, true, true};
  if (EPI == 1) {
    const float s1 = sinrev(1.0f / 8192.0f);
    beta = -5.0e-7f * s1 * s1 - H[(size_t)(bm >> 3) * 4190209u];  // 2*t(1) - H[m][0][0]
#pragma unroll
    for (int n = 0; n < 4; ++n) {
      const int ia = 2 * (bn * 256 + wc * 64 + n * 16 + lr) + h;  // i_true
      iok[n] = ia < 2047;
      const float s = sinrev((float)(ia + 1) * (1.0f / 8192.0f));
      tA[n] = -2.5e-7f * s * s;
    }
  }

  // ---- two-pass epilogue: 128-row halves through 64KB LDS
  float ssum = 0.f;
  unsigned short* gC = Cb + (size_t)(bm * 256) * 2048 + h * 1024 + bn * 256;
#pragma unroll
  for (int hh = 0; hh < 2; ++hh) {
    if (wr == hh) {
#pragma unroll
      for (int m = 0; m < 8; ++m) {
#pragma unroll
        for (int j = 0; j < 4; ++j) {
          const int row_l = wr * 128 + m * 16 + kg * 4 + j;
          const int row_h = row_l & 127;            // row within this half
          float tB = 0.f;
          bool jok = true;
          if (EPI == 1) {
            const int jint = (bm * 256 + row_l) & 2047;
            const int j_true = 2 * (jint & 1023) + (jint >> 10);
            jok = j_true < 2047;
            const float s = sinrev((float)(j_true + 1) * (1.0f / 8192.0f));
            tB = -2.5e-7f * s * s;
          }
#pragma unroll
          for (int n = 0; n < 4; ++n) {
            const int col_l = wc * 64 + n * 16 + lr;
            float v = acc[m][n][j];
            if (EPI == 1) {
              const float Hv = tA[n] + tB - beta;
              float r = __builtin_amdgcn_rcpf(Hv);
              r = r * (2.0f - Hv * r);           // 1 NR step
              v = (iok[n] && jok) ? v * r : 0.f;
            }
            if (EPI == 2) ssum += v;
            const int byte = row_h * 512 + ((((col_l >> 3) ^ (row_h & 7)) << 4)) + (col_l & 7) * 2;
            *(unsigned short*)&lds[byte] = f2b(v);
          }
        }
      }
    }
    __syncthreads();
    // coalesced flush: 128 rows x 512B contiguous
#pragma unroll
    for (int p = 0; p < 8; ++p) {
      const int c = p * 512 + tid;
      const int r = c >> 5, c16 = c & 31;
      const bf16x8 vv = *(const bf16x8*)&lds[r * 512 + ((c16 ^ (r & 7)) << 4)];
      *(bf16x8*)&gC[(size_t)(hh * 128 + r) * 2048 + c16 * 8] = vv;
    }
    if (hh == 0) __syncthreads();   // half-0 flush reads done before half-1 staging
  }

  if (EPI == 2) {
#pragma unroll
    for (int off = 32; off > 0; off >>= 1) ssum += __shfl_xor(ssum, off);
    if (lane == 0) atomicAdd(&sums[bm >> 3], ssum);
  }
}

// ---- final: de-interleave, homogeneous correction, mode->layer mix ----
__global__ __launch_bounds__(256)
void final_kernel(const unsigned short* __restrict__ V, const float* __restrict__ homsol,
                  const float* __restrict__ hm, const float* __restrict__ Cm2l,
                  const float* __restrict__ sums, float* __restrict__ out) {
  const int p = blockIdx.x * 256 + threadIdx.x;
  if (p >= 2049 * 2049) return;
  const int x = p / 2049, y = p - x * 2049;
  const bool interior = (x >= 1) && (x <= 2047) && (y >= 1) && (y <= 2047);
  int row = 0, col = 0;
  if (interior) {
    const int xt = x - 1, yt = y - 1;
    row = (xt & 1) ? 1024 + (xt >> 1) : (xt >> 1);
    col = (yt & 1) ? 1024 + (yt >> 1) : (yt >> 1);
  }
  float pm[4];
#pragma unroll
  for (int m = 0; m < 4; ++m) {
    float inner = 0.f;
    if (interior) inner = b2f(V[((size_t)m * 2048 + row) * 2048 + col]);
    const float alpha = -(sums[m] * (1.0f / 4194304.0f)) / hm[m];
    pm[m] = inner + alpha * homsol[(size_t)m * 4198401u + p];
  }
#pragma unroll
  for (int l = 0; l < 4; ++l) {
    out[(size_t)l * 4198401u + p] =
        Cm2l[l * 4 + 0] * pm[0] + Cm2l[l * 4 + 1] * pm[1] +
        Cm2l[l * 4 + 2] * pm[2] + Cm2l[l * 4 + 3] * pm[3];
  }
}

extern "C" void kernel_launch(void* const* d_in, const int* in_sizes, int n_in,
                              void* d_out, int out_size, void* d_ws, size_t ws_size,
                              hipStream_t stream) {
  const float* q     = (const float*)d_in[0];   // [4,2047,2047]
  const float* Cl2m  = (const float*)d_in[1];   // [4,4]
  const float* Cm2l  = (const float*)d_in[2];   // [4,4]
  const float* H     = (const float*)d_in[3];   // [4,2047,2047]
  const float* hom   = (const float*)d_in[4];   // [4,2049,2049]
  const float* hmean = (const float*)d_in[5];   // [4]
  float* out = (float*)d_out;

  char* ws = (char*)d_ws;
  unsigned short* Tb = (unsigned short*)ws;                    //  8 MB: TE1|TO1|TE3|TO3
  unsigned short* Aslot = (unsigned short*)(ws + 8388608u);    // 32 MB: [E half | O half]
  unsigned short* Bslot = (unsigned short*)(ws + 41943040u);   // 32 MB
  float* sums        = (float*)(ws + 75497472u);               // 16 B
  unsigned short* AO = Aslot + 8388608u;                       // O-half base

  tables_kernel<<<16384, 256, 0, stream>>>(Tb);
  mix_fold<<<8192, 256, 0, stream>>>(q, Cl2m, Aslot, AO);
  hipMemsetAsync(sums, 0, 16, stream);

  const dim3 tg(32, 16, 4);
  // G1: Q1 = fold(P) x S  (DST along y)
  gemm_eo<0><<<256, 512, 0, stream>>>(Aslot, Tb, Bslot, nullptr, nullptr);
  // transpose + natural fold over x
  tfold<0><<<tg, 256, 0, stream>>>(Bslot, Aslot, AO);
  // G2: R = (fold(Q1^T) x S) / H  (DST along x; H computed in-epilogue)
  gemm_eo<1><<<256, 512, 0, stream>>>(Aslot, Tb, Bslot, H, nullptr);
  // interleaved column fold over spectral-x
  fold_cols<<<32768, 256, 0, stream>>>(Bslot, Aslot, AO);
  // G3: U = fold(R) x S  (inverse DST step 1) -- interleaved-fold tables
  gemm_eo<0><<<256, 512, 0, stream>>>(Aslot, Tb + 2097152u, Bslot, nullptr, nullptr);
  // transpose + interleaved fold over spectral-y
  tfold<1><<<tg, 256, 0, stream>>>(Bslot, Aslot, AO);
  // G4: V = fold(U^T) x S (+ per-mode sum)
  gemm_eo<2><<<256, 512, 0, stream>>>(Aslot, Tb + 2097152u, Bslot, nullptr, sums);

  final_kernel<<<16401, 256, 0, stream>>>(Bslot, hom, hmean, Cm2l, sums, out);
}

// Round 16
// 300.168 us; speedup vs baseline: 3.5103x; 3.5103x over previous
//
#include <hip/hip_runtime.h>

// DST-I spectral Helmholtz solver, NZ=4, NX=NY=2048.
// Even/odd mirror-fold (half FLOPs); B from transposed tables (L3-hot);
// GEMM: 128x128 tile, BK=64, 64KB LDS -> 2 independent blocks/CU (cross-block
// stall hiding), r12's 8-slot XOR swizzle, compiler-scheduled interior,
// 1 barrier/K-tile; LDS-staged coalesced C writes; G2 computes H in-epilogue.

typedef __attribute__((ext_vector_type(8))) short bf16x8;
typedef __attribute__((ext_vector_type(4))) float f32x4;
typedef __attribute__((ext_vector_type(8))) unsigned short ushort8;

#define LDS_SPACE __attribute__((address_space(3)))
#define GLB_SPACE __attribute__((address_space(1)))

__device__ __forceinline__ void gld_lds16(const unsigned short* g, unsigned short* l) {
  __builtin_amdgcn_global_load_lds((const GLB_SPACE void*)g, (LDS_SPACE void*)l, 16, 0, 0);
}

__device__ __forceinline__ float sinrev(float rev) {   // sin(2*pi*rev), exact arg
  float r;
  asm("v_sin_f32 %0, %1" : "=v"(r) : "v"(rev));
  return r;
}

__device__ __forceinline__ unsigned short f2b(float f) {
  union { float f; unsigned u; } v; v.f = f;
  unsigned r = (v.u + 0x7fffu + ((v.u >> 16) & 1u)) >> 16;  // RNE
  return (unsigned short)r;
}
__device__ __forceinline__ float b2f(unsigned short u) {
  union { unsigned u; float f; } v; v.u = ((unsigned)u) << 16;
  return v.f;
}

// ---- tables: T[tbl][n][k] (transposed), bf16.  0:TE1 1:TO1 2:TE3 3:TO3 ----
__global__ __launch_bounds__(256)
void tables_kernel(unsigned short* __restrict__ T) {
  const int idx = blockIdx.x * 256 + threadIdx.x;     // < 4*1024*1024
  const int tbl = idx >> 20, n = (idx >> 10) & 1023, k = idx & 1023;
  int a;
  if (tbl < 2) a = k;                                  // natural pair-rep order
  else a = (k < 512) ? 2 * k : (k < 1023 ? 2 * (k - 512) + 1 : 1023);
  const int cp1 = (tbl & 1) ? 2 * n + 2 : 2 * n + 1;   // j_true+1
  const int ph = ((a + 1) * cp1) & 4095;               // exact phase mod 2*pi
  const float v = 0.03125f * sinrev((float)ph * (1.0f / 4096.0f));
  T[idx] = f2b(v);
}

// ---- mix + natural fold along y: AE/AO [4*2048 x 1024] bf16 ----
__global__ __launch_bounds__(256)
void mix_fold(const float* __restrict__ q, const float* __restrict__ Cl2m,
              unsigned short* __restrict__ AE, unsigned short* __restrict__ AO) {
  const int idx = blockIdx.x * 256 + threadIdx.x;     // < 2048*1024
  const int x = idx >> 10, u = idx & 1023;
  float c[16];
#pragma unroll
  for (int i = 0; i < 16; ++i) c[i] = Cl2m[i];
  float fe[4] = {0.f, 0.f, 0.f, 0.f}, fo[4] = {0.f, 0.f, 0.f, 0.f};
  if (x < 2047) {
#pragma unroll
    for (int l = 0; l < 4; ++l) {
      const size_t base = ((size_t)l * 2047 + x) * 2047;
      const float qa = q[base + u];
      const float qb = (u < 1023) ? q[base + 2046 - u] : 0.f;
      const float E = (u == 1023) ? qa : qa + qb;
      const float O = (u == 1023) ? 0.f : qa - qb;
#pragma unroll
      for (int m = 0; m < 4; ++m) { fe[m] += c[m * 4 + l] * E; fo[m] += c[m * 4 + l] * O; }
    }
  }
#pragma unroll
  for (int m = 0; m < 4; ++m) {
    AE[((size_t)m * 2048 + x) * 1024 + u] = f2b(fe[m]);
    AO[((size_t)m * 2048 + x) * 1024 + u] = f2b(fo[m]);
  }
}

// ---- transpose + fold (per mode): out[c][u] = in[r1(u)][c] +/- in[r2(u)][c] ----
template <int MAP>
__global__ __launch_bounds__(256)
void tfold(const unsigned short* __restrict__ in, unsigned short* __restrict__ outE,
           unsigned short* __restrict__ outO) {
  __shared__ unsigned short t1[64][72];
  __shared__ unsigned short t2[64][72];
  const size_t ib = (size_t)blockIdx.z * (2048u * 2048u);
  const size_t ob = (size_t)blockIdx.z * (2048u * 1024u);
  const int c0 = blockIdx.x * 64, u0 = blockIdx.y * 64;
  const int t = threadIdx.x;
  const int rr = t >> 3, cc = (t & 7) * 8;
#pragma unroll
  for (int ch = 0; ch < 2; ++ch) {
    const int r = ch * 32 + rr, u = u0 + r;
    const int r1 = (MAP == 0) ? u : (u < 512 ? u : 1024 + (u - 512));
    const int r2 = (MAP == 0) ? 2046 - u : (u < 512 ? 1023 - u : 2046 - (u - 512));
    ushort8 v1 = *(const ushort8*)&in[ib + (size_t)r1 * 2048 + c0 + cc];
    ushort8 v2 = *(const ushort8*)&in[ib + (size_t)r2 * 2048 + c0 + cc];
#pragma unroll
    for (int j = 0; j < 8; ++j) { t1[r][cc + j] = v1[j]; t2[r][cc + j] = v2[j]; }
  }
  __syncthreads();
#pragma unroll
  for (int ch = 0; ch < 2; ++ch) {
    const int r = ch * 32 + rr;
    ushort8 vE, vO;
#pragma unroll
    for (int j = 0; j < 8; ++j) {
      const int uu = u0 + cc + j;
      const float a = b2f(t1[cc + j][r]);
      const float b = b2f(t2[cc + j][r]);
      vE[j] = f2b((uu == 1023) ? a : a + b);
      vO[j] = f2b((uu == 1023) ? 0.f : a - b);
    }
    const size_t o = ob + (size_t)(c0 + r) * 1024 + u0 + cc;
    *(ushort8*)&outE[o] = vE;
    *(ushort8*)&outO[o] = vO;
  }
}

// ---- column fold over interleaved axis (no transpose): pre-G3 ----
__global__ __launch_bounds__(256)
void fold_cols(const unsigned short* __restrict__ R, unsigned short* __restrict__ AE,
               unsigned short* __restrict__ AO) {
  const int idx = blockIdx.x * 256 + threadIdx.x;     // < 8192*1024
  const int row = idx >> 10, u = idx & 1023;
  const int c1 = (u < 512) ? u : (u < 1023 ? 512 + u : 1535);
  const int c2 = (u < 512) ? 1023 - u : (u < 1023 ? 2558 - u : 1535);
  const float a = b2f(R[(size_t)row * 2048 + c1]);
  const float b = b2f(R[(size_t)row * 2048 + c2]);
  AE[(size_t)row * 1024 + u] = f2b((u == 1023) ? a : a + b);
  AO[(size_t)row * 1024 + u] = f2b((u == 1023) ? 0.f : a - b);
}

// ---- GEMM: C_half[8192x1024] = A_half[8192x1024] * T_half^T ----
// 128x128 tile, BK=64, 4 waves (2x2), 64KB LDS -> 2 blocks/CU.
// EPI 0: plain. EPI 1: divide by H computed in-epilogue. EPI 2: + per-mode sum.
#define MFMA_BF16 __builtin_amdgcn_mfma_f32_16x16x32_bf16

template <int EPI>
__global__ __launch_bounds__(256, 2)
void gemm_eo(const unsigned short* __restrict__ A, const unsigned short* __restrict__ T,
             unsigned short* __restrict__ Cb, const float* __restrict__ H,
             float* __restrict__ sums) {
  __shared__ __align__(16) char lds[65536];  // 2 x (A 16KB + B 16KB); epi: 32KB C tile
  const int bid = blockIdx.x;                // 1024 blocks
  const int xcd = bid & 7, idx = bid >> 3;   // 128 blocks per XCD
  const int bm = xcd * 8 + (idx >> 4);       // 8 bm per XCD -> A panels L2-resident
  const int rest = idx & 15;
  const int h = rest & 1, bn = rest >> 1;    // h 0..1, bn 0..7
  const int tid = threadIdx.x;
  const int lane = tid & 63, wave = tid >> 6;
  const int wr = wave >> 1, wc = wave & 1;   // 2 x 2 wave grid (64x64 per wave)
  const int lr = lane & 15, kg = lane >> 4;
  const int x7 = lr & 7;

  const unsigned short* gA = A + (size_t)h * 8388608u + (size_t)bm * 128 * 1024;
  const unsigned short* gB = T + (size_t)h * 1048576u + (size_t)bn * 128 * 1024;

  // staging: 16B slot ps; row = ps>>3; k-col16 = (ps&7)^(row&7)  (r12 swizzle)
  auto stage = [&](int kt, int c) {
    char* lc = lds + c * 32768;
#pragma unroll
    for (int i = 0; i < 4; ++i) {
      const int ps = tid + i * 256;
      const int row = ps >> 3;
      const int slot = (ps & 7) ^ (row & 7);
      gld_lds16(gA + (size_t)row * 1024 + kt * 64 + slot * 8,
                (unsigned short*)(lc + ps * 16));
    }
#pragma unroll
    for (int i = 0; i < 4; ++i) {
      const int ps = tid + i * 256;
      const int row = ps >> 3;
      const int slot = (ps & 7) ^ (row & 7);
      gld_lds16(gB + (size_t)row * 1024 + kt * 64 + slot * 8,
                (unsigned short*)(lc + 16384 + ps * 16));
    }
  };

  f32x4 acc[4][4];
#pragma unroll
  for (int m = 0; m < 4; ++m)
#pragma unroll
    for (int n = 0; n < 4; ++n) acc[m][n] = (f32x4){0.f, 0.f, 0.f, 0.f};

  stage(0, 0);
  stage(1, 1);
  __syncthreads();   // tiles 0,1 staged + published

  const int arow = wr * 64 + lr;
  const int brow = wc * 64 + lr;
  const LDS_SPACE char* lbase = (const LDS_SPACE char*)lds;

  for (int t = 0; t < 16; ++t) {
    const LDS_SPACE char* la = lbase + (t & 1) * 32768;
    const LDS_SPACE char* lb = la + 16384;

    bf16x8 av[4][2], bv[4][2];
    // plain LDS vector loads — compiler schedules reads<->MFMAs with counted lgkmcnt
#pragma unroll
    for (int m = 0; m < 4; ++m)
#pragma unroll
      for (int ks = 0; ks < 2; ++ks)
        av[m][ks] = *(const LDS_SPACE bf16x8*)(la + (arow + m * 16) * 128 + (((ks * 4 + kg) ^ x7) << 4));
#pragma unroll
    for (int n = 0; n < 4; ++n)
#pragma unroll
      for (int ks = 0; ks < 2; ++ks)
        bv[n][ks] = *(const LDS_SPACE bf16x8*)(lb + (brow + n * 16) * 128 + (((ks * 4 + kg) ^ x7) << 4));

#pragma unroll
    for (int ks = 0; ks < 2; ++ks)
#pragma unroll
      for (int m = 0; m < 4; ++m)
#pragma unroll
        for (int n = 0; n < 4; ++n)
          acc[m][n] = MFMA_BF16(av[m][ks], bv[n][ks], acc[m][n], 0, 0, 0);

    // ONE barrier per K-tile: all waves done reading buf[t&1]; drains staging
    // issued last iteration (landed: 1 full tile in flight) and publishes it.
    __syncthreads();
    if (t < 14) stage(t + 2, t & 1);
  }

  // ---- EPI1 constants: H(a,b) = t(a+1)+t(b+1)-beta, t(x) = -2.5e-7*sin^2(pi*x/4096)
  float beta = 0.f, tA[4];
  bool iok[4] = {true, true, true, true};
  if (EPI == 1) {
    const float s1 = sinrev(1.0f / 8192.0f);
    beta = -5.0e-7f * s1 * s1 - H[(size_t)(bm >> 4) * 4190209u];  // 2*t(1) - H[m][0][0]
#pragma unroll
    for (int n = 0; n < 4; ++n) {
      const int ia = 2 * (bn * 128 + wc * 64 + n * 16 + lr) + h;  // i_true
      iok[n] = ia < 2047;
      const float s = sinrev((float)(ia + 1) * (1.0f / 8192.0f));
      tA[n] = -2.5e-7f * s * s;
    }
  }

  // ---- stage C tile (128x128) into LDS (XOR-swizzled 16B slots per 256B row)
  float ssum = 0.f;
#pragma unroll
  for (int m = 0; m < 4; ++m) {
#pragma unroll
    for (int j = 0; j < 4; ++j) {
      const int row_l = wr * 64 + m * 16 + kg * 4 + j;
      float tB = 0.f;
      bool jok = true;
      if (EPI == 1) {
        const int jint = (bm * 128 + row_l) & 2047;
        const int j_true = 2 * (jint & 1023) + (jint >> 10);
        jok = j_true < 2047;
        const float s = sinrev((float)(j_true + 1) * (1.0f / 8192.0f));
        tB = -2.5e-7f * s * s;
      }
#pragma unroll
      for (int n = 0; n < 4; ++n) {
        const int col_l = wc * 64 + n * 16 + lr;
        float v = acc[m][n][j];
        if (EPI == 1) {
          const float Hv = tA[n] + tB - beta;
          float r = __builtin_amdgcn_rcpf(Hv);
          r = r * (2.0f - Hv * r);           // 1 NR step
          v = (iok[n] && jok) ? v * r : 0.f;
        }
        if (EPI == 2) ssum += v;
        const int byte = row_l * 256 + ((((col_l >> 3) ^ (row_l & 7)) << 4)) + (col_l & 7) * 2;
        *(unsigned short*)&lds[byte] = f2b(v);
      }
    }
  }
  __syncthreads();

  // ---- coalesced flush: 128 rows x 256B contiguous
  unsigned short* gC = Cb + (size_t)(bm * 128) * 2048 + h * 1024 + bn * 128;
#pragma unroll
  for (int p = 0; p < 8; ++p) {
    const int c = p * 256 + tid;
    const int r = c >> 4, c16 = c & 15;
    const bf16x8 vv = *(const bf16x8*)&lds[r * 256 + ((c16 ^ (r & 7)) << 4)];
    *(bf16x8*)&gC[(size_t)r * 2048 + c16 * 8] = vv;
  }

  if (EPI == 2) {
#pragma unroll
    for (int off = 32; off > 0; off >>= 1) ssum += __shfl_xor(ssum, off);
    if (lane == 0) atomicAdd(&sums[bm >> 4], ssum);
  }
}

// ---- final: de-interleave, homogeneous correction, mode->layer mix ----
__global__ __launch_bounds__(256)
void final_kernel(const unsigned short* __restrict__ V, const float* __restrict__ homsol,
                  const float* __restrict__ hm, const float* __restrict__ Cm2l,
                  const float* __restrict__ sums, float* __restrict__ out) {
  const int p = blockIdx.x * 256 + threadIdx.x;
  if (p >= 2049 * 2049) return;
  const int x = p / 2049, y = p - x * 2049;
  const bool interior = (x >= 1) && (x <= 2047) && (y >= 1) && (y <= 2047);
  int row = 0, col = 0;
  if (interior) {
    const int xt = x - 1, yt = y - 1;
    row = (xt & 1) ? 1024 + (xt >> 1) : (xt >> 1);
    col = (yt & 1) ? 1024 + (yt >> 1) : (yt >> 1);
  }
  float pm[4];
#pragma unroll
  for (int m = 0; m < 4; ++m) {
    float inner = 0.f;
    if (interior) inner = b2f(V[((size_t)m * 2048 + row) * 2048 + col]);
    const float alpha = -(sums[m] * (1.0f / 4194304.0f)) / hm[m];
    pm[m] = inner + alpha * homsol[(size_t)m * 4198401u + p];
  }
#pragma unroll
  for (int l = 0; l < 4; ++l) {
    out[(size_t)l * 4198401u + p] =
        Cm2l[l * 4 + 0] * pm[0] + Cm2l[l * 4 + 1] * pm[1] +
        Cm2l[l * 4 + 2] * pm[2] + Cm2l[l * 4 + 3] * pm[3];
  }
}

extern "C" void kernel_launch(void* const* d_in, const int* in_sizes, int n_in,
                              void* d_out, int out_size, void* d_ws, size_t ws_size,
                              hipStream_t stream) {
  const float* q     = (const float*)d_in[0];   // [4,2047,2047]
  const float* Cl2m  = (const float*)d_in[1];   // [4,4]
  const float* Cm2l  = (const float*)d_in[2];   // [4,4]
  const float* H     = (const float*)d_in[3];   // [4,2047,2047]
  const float* hom   = (const float*)d_in[4];   // [4,2049,2049]
  const float* hmean = (const float*)d_in[5];   // [4]
  float* out = (float*)d_out;

  char* ws = (char*)d_ws;
  unsigned short* Tb = (unsigned short*)ws;                    //  8 MB: TE1|TO1|TE3|TO3
  unsigned short* Aslot = (unsigned short*)(ws + 8388608u);    // 32 MB: [E half | O half]
  unsigned short* Bslot = (unsigned short*)(ws + 41943040u);   // 32 MB
  float* sums        = (float*)(ws + 75497472u);               // 16 B
  unsigned short* AO = Aslot + 8388608u;                       // O-half base

  tables_kernel<<<16384, 256, 0, stream>>>(Tb);
  mix_fold<<<8192, 256, 0, stream>>>(q, Cl2m, Aslot, AO);
  hipMemsetAsync(sums, 0, 16, stream);

  const dim3 tg(32, 16, 4);
  // G1: Q1 = fold(P) x S  (DST along y)
  gemm_eo<0><<<1024, 256, 0, stream>>>(Aslot, Tb, Bslot, nullptr, nullptr);
  // transpose + natural fold over x
  tfold<0><<<tg, 256, 0, stream>>>(Bslot, Aslot, AO);
  // G2: R = (fold(Q1^T) x S) / H  (DST along x; H computed in-epilogue)
  gemm_eo<1><<<1024, 256, 0, stream>>>(Aslot, Tb, Bslot, H, nullptr);
  // interleaved column fold over spectral-x
  fold_cols<<<32768, 256, 0, stream>>>(Bslot, Aslot, AO);
  // G3: U = fold(R) x S  (inverse DST step 1) -- interleaved-fold tables
  gemm_eo<0><<<1024, 256, 0, stream>>>(Aslot, Tb + 2097152u, Bslot, nullptr, nullptr);
  // transpose + interleaved fold over spectral-y
  tfold<1><<<tg, 256, 0, stream>>>(Bslot, Aslot, AO);
  // G4: V = fold(U^T) x S (+ per-mode sum)
  gemm_eo<2><<<1024, 256, 0, stream>>>(Aslot, Tb + 2097152u, Bslot, nullptr, sums);

  final_kernel<<<16401, 256, 0, stream>>>(Bslot, hom, hmean, Cm2l, sums, out);
}

// Round 18
// 263.910 us; speedup vs baseline: 3.9926x; 1.1374x over previous
//
#include <hip/hip_runtime.h>

// DST-I spectral Helmholtz solver, NZ=4, NX=NY=2048.
// Even/odd mirror-fold (half FLOPs); B from transposed tables (L3-hot);
// GEMM (r12, best measured): 256x256 tile, BK=64 dbuf, compiler-scheduled
// interior, ONE __syncthreads per K-tile; LDS-staged coalesced C writes;
// G2 computes H in-epilogue (sin^2 form). This round: pair-coalesced final
// kernel + vectorized tables kernel.

typedef __attribute__((ext_vector_type(8))) short bf16x8;
typedef __attribute__((ext_vector_type(4))) float f32x4;
typedef __attribute__((ext_vector_type(8))) unsigned short ushort8;
typedef __attribute__((ext_vector_type(4))) unsigned short ushort4v;
typedef __attribute__((ext_vector_type(2))) float float2v;

#define LDS_SPACE __attribute__((address_space(3)))
#define GLB_SPACE __attribute__((address_space(1)))

__device__ __forceinline__ void gld_lds16(const unsigned short* g, unsigned short* l) {
  __builtin_amdgcn_global_load_lds((const GLB_SPACE void*)g, (LDS_SPACE void*)l, 16, 0, 0);
}

__device__ __forceinline__ float sinrev(float rev) {   // sin(2*pi*rev), exact arg
  float r;
  asm("v_sin_f32 %0, %1" : "=v"(r) : "v"(rev));
  return r;
}

__device__ __forceinline__ unsigned short f2b(float f) {
  union { float f; unsigned u; } v; v.f = f;
  unsigned r = (v.u + 0x7fffu + ((v.u >> 16) & 1u)) >> 16;  // RNE
  return (unsigned short)r;
}
__device__ __forceinline__ float b2f(unsigned short u) {
  union { unsigned u; float f; } v; v.u = ((unsigned)u) << 16;
  return v.f;
}

// ---- tables: T[tbl][n][k] (transposed), bf16.  0:TE1 1:TO1 2:TE3 3:TO3 ----
__global__ __launch_bounds__(256)
void tables_kernel(unsigned short* __restrict__ T) {
  const int base = (blockIdx.x * 256 + threadIdx.x) * 4;   // < 4*1024*1024
  const int tbl = base >> 20, n = (base >> 10) & 1023, k0 = base & 1023;
  const int cp1 = (tbl & 1) ? 2 * n + 2 : 2 * n + 1;       // j_true+1
  ushort4v v;
#pragma unroll
  for (int e = 0; e < 4; ++e) {
    const int k = k0 + e;
    int a;
    if (tbl < 2) a = k;                                    // natural pair-rep order
    else a = (k < 512) ? 2 * k : (k < 1023 ? 2 * (k - 512) + 1 : 1023);
    const int ph = ((a + 1) * cp1) & 4095;                 // exact phase mod 2*pi
    v[e] = f2b(0.03125f * sinrev((float)ph * (1.0f / 4096.0f)));
  }
  *(ushort4v*)&T[base] = v;
}

// ---- mix + natural fold along y: AE/AO [4*2048 x 1024] bf16 ----
__global__ __launch_bounds__(256)
void mix_fold(const float* __restrict__ q, const float* __restrict__ Cl2m,
              unsigned short* __restrict__ AE, unsigned short* __restrict__ AO) {
  const int idx = blockIdx.x * 256 + threadIdx.x;     // < 2048*1024
  const int x = idx >> 10, u = idx & 1023;
  float c[16];
#pragma unroll
  for (int i = 0; i < 16; ++i) c[i] = Cl2m[i];
  float fe[4] = {0.f, 0.f, 0.f, 0.f}, fo[4] = {0.f, 0.f, 0.f, 0.f};
  if (x < 2047) {
#pragma unroll
    for (int l = 0; l < 4; ++l) {
      const size_t base = ((size_t)l * 2047 + x) * 2047;
      const float qa = q[base + u];
      const float qb = (u < 1023) ? q[base + 2046 - u] : 0.f;
      const float E = (u == 1023) ? qa : qa + qb;
      const float O = (u == 1023) ? 0.f : qa - qb;
#pragma unroll
      for (int m = 0; m < 4; ++m) { fe[m] += c[m * 4 + l] * E; fo[m] += c[m * 4 + l] * O; }
    }
  }
#pragma unroll
  for (int m = 0; m < 4; ++m) {
    AE[((size_t)m * 2048 + x) * 1024 + u] = f2b(fe[m]);
    AO[((size_t)m * 2048 + x) * 1024 + u] = f2b(fo[m]);
  }
}

// ---- transpose + fold (per mode): out[c][u] = in[r1(u)][c] +/- in[r2(u)][c] ----
template <int MAP>
__global__ __launch_bounds__(256)
void tfold(const unsigned short* __restrict__ in, unsigned short* __restrict__ outE,
           unsigned short* __restrict__ outO) {
  __shared__ unsigned short t1[64][72];
  __shared__ unsigned short t2[64][72];
  const size_t ib = (size_t)blockIdx.z * (2048u * 2048u);
  const size_t ob = (size_t)blockIdx.z * (2048u * 1024u);
  const int c0 = blockIdx.x * 64, u0 = blockIdx.y * 64;
  const int t = threadIdx.x;
  const int rr = t >> 3, cc = (t & 7) * 8;
#pragma unroll
  for (int ch = 0; ch < 2; ++ch) {
    const int r = ch * 32 + rr, u = u0 + r;
    const int r1 = (MAP == 0) ? u : (u < 512 ? u : 1024 + (u - 512));
    const int r2 = (MAP == 0) ? 2046 - u : (u < 512 ? 1023 - u : 2046 - (u - 512));
    ushort8 v1 = *(const ushort8*)&in[ib + (size_t)r1 * 2048 + c0 + cc];
    ushort8 v2 = *(const ushort8*)&in[ib + (size_t)r2 * 2048 + c0 + cc];
#pragma unroll
    for (int j = 0; j < 8; ++j) { t1[r][cc + j] = v1[j]; t2[r][cc + j] = v2[j]; }
  }
  __syncthreads();
#pragma unroll
  for (int ch = 0; ch < 2; ++ch) {
    const int r = ch * 32 + rr;
    ushort8 vE, vO;
#pragma unroll
    for (int j = 0; j < 8; ++j) {
      const int uu = u0 + cc + j;
      const float a = b2f(t1[cc + j][r]);
      const float b = b2f(t2[cc + j][r]);
      vE[j] = f2b((uu == 1023) ? a : a + b);
      vO[j] = f2b((uu == 1023) ? 0.f : a - b);
    }
    const size_t o = ob + (size_t)(c0 + r) * 1024 + u0 + cc;
    *(ushort8*)&outE[o] = vE;
    *(ushort8*)&outO[o] = vO;
  }
}

// ---- column fold over interleaved axis (no transpose): pre-G3 ----
__global__ __launch_bounds__(256)
void fold_cols(const unsigned short* __restrict__ R, unsigned short* __restrict__ AE,
               unsigned short* __restrict__ AO) {
  const int idx = blockIdx.x * 256 + threadIdx.x;     // < 8192*1024
  const int row = idx >> 10, u = idx & 1023;
  const int c1 = (u < 512) ? u : (u < 1023 ? 512 + u : 1535);
  const int c2 = (u < 512) ? 1023 - u : (u < 1023 ? 2558 - u : 1535);
  const float a = b2f(R[(size_t)row * 2048 + c1]);
  const float b = b2f(R[(size_t)row * 2048 + c2]);
  AE[(size_t)row * 1024 + u] = f2b((u == 1023) ? a : a + b);
  AO[(size_t)row * 1024 + u] = f2b((u == 1023) ? 0.f : a - b);
}

// ---- GEMM: C_half[8192x1024] = A_half[8192x1024] * T_half^T ----
// EPI 0: plain. EPI 1: divide by H computed in-epilogue. EPI 2: + per-mode sum.
#define MFMA_BF16 __builtin_amdgcn_mfma_f32_16x16x32_bf16

template <int EPI>
__global__ __launch_bounds__(512, 2)
void gemm_eo(const unsigned short* __restrict__ A, const unsigned short* __restrict__ T,
             unsigned short* __restrict__ Cb, const float* __restrict__ H,
             float* __restrict__ sums) {
  __shared__ __align__(16) char lds[131072];  // K-loop: dbuf A|B; epilogue: 256x256 bf16 C
  const int bid = blockIdx.x;
  const int swz = (bid & 7) * 32 + (bid >> 3);      // XCD-bijective (256 % 8 == 0)
  const int h = swz & 1;                            // 0: even(E), 1: odd(O)
  const int bn = (swz >> 1) & 3, bm = swz >> 3;
  const int tid = threadIdx.x;
  const int lane = tid & 63, wave = tid >> 6;
  const int wr = wave >> 2, wc = wave & 3;          // 2 x 4 wave grid
  const int lr = lane & 15, kg = lane >> 4;
  const int x7 = lr & 7;

  const unsigned short* gA = A + (size_t)h * 8388608u + (size_t)bm * 256 * 1024;
  const unsigned short* gB = T + (size_t)h * 1048576u + (size_t)bn * 256 * 1024;

  // staging: 16B slot ps = tid + i*512; row = ps>>3; k-col16 = (ps&7)^(row&7)
  const int row0 = tid >> 3;
  const int slot = (tid & 7) ^ (row0 & 7);

  auto stage = [&](int kt, int c) {
    char* lc = lds + c * 65536;
    const size_t ko = (size_t)kt * 64 + slot * 8;
#pragma unroll
    for (int i = 0; i < 4; ++i)
      gld_lds16(gA + (size_t)(row0 + i * 64) * 1024 + ko,
                (unsigned short*)(lc + (tid + i * 512) * 16));
#pragma unroll
    for (int i = 0; i < 4; ++i)
      gld_lds16(gB + (size_t)(row0 + i * 64) * 1024 + ko,
                (unsigned short*)(lc + 32768 + (tid + i * 512) * 16));
  };

  f32x4 acc[8][4];
#pragma unroll
  for (int m = 0; m < 8; ++m)
#pragma unroll
    for (int n = 0; n < 4; ++n) acc[m][n] = (f32x4){0.f, 0.f, 0.f, 0.f};

  stage(0, 0);
  stage(1, 1);
  __syncthreads();   // tile 0 (and 1) staging drained + published

  const int arow = wr * 128 + lr;
  const int brow = wc * 64 + lr;
  const LDS_SPACE char* lbase = (const LDS_SPACE char*)lds;

  for (int t = 0; t < 16; ++t) {
    const LDS_SPACE char* la = lbase + (t & 1) * 65536;
    const LDS_SPACE char* lb = la + 32768;

    bf16x8 al[4][2], ah[4][2], bl[2][2], bh[2][2];

    // plain LDS vector loads — compiler schedules reads<->MFMAs with counted lgkmcnt
#pragma unroll
    for (int m = 0; m < 4; ++m)
#pragma unroll
      for (int ks = 0; ks < 2; ++ks)
        al[m][ks] = *(const LDS_SPACE bf16x8*)(la + (arow + m * 16) * 128 + (((ks * 4 + kg) ^ x7) << 4));
#pragma unroll
    for (int n = 0; n < 2; ++n)
#pragma unroll
      for (int ks = 0; ks < 2; ++ks)
        bl[n][ks] = *(const LDS_SPACE bf16x8*)(lb + (brow + n * 16) * 128 + (((ks * 4 + kg) ^ x7) << 4));
#pragma unroll
    for (int ks = 0; ks < 2; ++ks)
#pragma unroll
      for (int m = 0; m < 4; ++m)
#pragma unroll
        for (int n = 0; n < 2; ++n)
          acc[m][n] = MFMA_BF16(al[m][ks], bl[n][ks], acc[m][n], 0, 0, 0);

#pragma unroll
    for (int n = 0; n < 2; ++n)
#pragma unroll
      for (int ks = 0; ks < 2; ++ks)
        bh[n][ks] = *(const LDS_SPACE bf16x8*)(lb + (brow + (n + 2) * 16) * 128 + (((ks * 4 + kg) ^ x7) << 4));
#pragma unroll
    for (int ks = 0; ks < 2; ++ks)
#pragma unroll
      for (int m = 0; m < 4; ++m)
#pragma unroll
        for (int n = 0; n < 2; ++n)
          acc[m][n + 2] = MFMA_BF16(al[m][ks], bh[n][ks], acc[m][n + 2], 0, 0, 0);

#pragma unroll
    for (int m = 0; m < 4; ++m)
#pragma unroll
      for (int ks = 0; ks < 2; ++ks)
        ah[m][ks] = *(const LDS_SPACE bf16x8*)(la + (arow + (m + 4) * 16) * 128 + (((ks * 4 + kg) ^ x7) << 4));
#pragma unroll
    for (int ks = 0; ks < 2; ++ks)
#pragma unroll
      for (int m = 0; m < 4; ++m)
#pragma unroll
        for (int n = 0; n < 2; ++n)
          acc[m + 4][n + 2] = MFMA_BF16(ah[m][ks], bh[n][ks], acc[m + 4][n + 2], 0, 0, 0);
#pragma unroll
    for (int ks = 0; ks < 2; ++ks)
#pragma unroll
      for (int m = 0; m < 4; ++m)
#pragma unroll
        for (int n = 0; n < 2; ++n)
          acc[m + 4][n] = MFMA_BF16(ah[m][ks], bl[n][ks], acc[m + 4][n], 0, 0, 0);

    // ONE barrier per K-tile: all waves done reading buf[t&1]; drains staging
    // issued last iteration (landed: >1 tile in flight) and publishes it.
    __syncthreads();
    if (t < 14) stage(t + 2, t & 1);
  }

  // ---- EPI1 constants: H(a,b) = t(a+1)+t(b+1)-beta, t(x) = -2.5e-7*sin^2(pi*x/4096)
  float beta = 0.f, tA[4];
  bool iok[4] = {true, true, true, true};
  if (EPI == 1) {
    const float s1 = sinrev(1.0f / 8192.0f);
    beta = -5.0e-7f * s1 * s1 - H[(size_t)(bm >> 3) * 4190209u];  // 2*t(1) - H[m][0][0]
#pragma unroll
    for (int n = 0; n < 4; ++n) {
      const int ia = 2 * (bn * 256 + wc * 64 + n * 16 + lr) + h;  // i_true
      iok[n] = ia < 2047;
      const float s = sinrev((float)(ia + 1) * (1.0f / 8192.0f));
      tA[n] = -2.5e-7f * s * s;
    }
  }

  // ---- stage C tile into LDS (XOR-swizzled 16B slots within each 512B row)
  float ssum = 0.f;
#pragma unroll
  for (int m = 0; m < 8; ++m) {
#pragma unroll
    for (int j = 0; j < 4; ++j) {
      const int row_l = wr * 128 + m * 16 + kg * 4 + j;
      float tB = 0.f;
      bool jok = true;
      if (EPI == 1) {
        const int jint = (bm * 256 + row_l) & 2047;
        const int j_true = 2 * (jint & 1023) + (jint >> 10);
        jok = j_true < 2047;
        const float s = sinrev((float)(j_true + 1) * (1.0f / 8192.0f));
        tB = -2.5e-7f * s * s;
      }
#pragma unroll
      for (int n = 0; n < 4; ++n) {
        const int col_l = wc * 64 + n * 16 + lr;
        float v = acc[m][n][j];
        if (EPI == 1) {
          const float Hv = tA[n] + tB - beta;
          float r = __builtin_amdgcn_rcpf(Hv);
          r = r * (2.0f - Hv * r);           // 1 NR step
          v = (iok[n] && jok) ? v * r : 0.f;
        }
        if (EPI == 2) ssum += v;
        const int byte = row_l * 512 + ((((col_l >> 3) ^ (row_l & 7)) << 4)) + (col_l & 7) * 2;
        *(unsigned short*)&lds[byte] = f2b(v);
      }
    }
  }
  __syncthreads();

  // ---- coalesced flush: 256 rows x 512B contiguous
  unsigned short* gC = Cb + (size_t)(bm * 256) * 2048 + h * 1024 + bn * 256;
#pragma unroll
  for (int p = 0; p < 16; ++p) {
    const int c = p * 512 + tid;
    const int r = c >> 5, c16 = c & 31;
    const bf16x8 vv = *(const bf16x8*)&lds[r * 512 + ((c16 ^ (r & 7)) << 4)];
    *(bf16x8*)&gC[(size_t)r * 2048 + c16 * 8] = vv;
  }

  if (EPI == 2) {
#pragma unroll
    for (int off = 32; off > 0; off >>= 1) ssum += __shfl_xor(ssum, off);
    if (lane == 0) atomicAdd(&sums[bm >> 3], ssum);
  }
}

// ---- final: de-interleave, homogeneous correction, mode->layer mix ----
// One thread per (x, y-pair): both V gathers become coalesced streams.
__global__ __launch_bounds__(256)
void final_kernel(const unsigned short* __restrict__ V, const float* __restrict__ homsol,
                  const float* __restrict__ hm, const float* __restrict__ Cm2l,
                  const float* __restrict__ sums, float* __restrict__ out) {
  const int pp = blockIdx.x * 256 + threadIdx.x;    // < 2049*1025
  if (pp >= 2049 * 1025) return;
  const int x = pp / 1025, yy = pp - x * 1025;
  const int y0 = 2 * yy;                            // even y
  const bool has1 = (y0 + 1) <= 2048;               // odd y exists
  const bool xin = (x >= 1) && (x <= 2047);
  // y0 interior: y0>=1 && y0<=2047 -> yy>=1 && y0!=2048; yt0 = y0-1 (odd)
  const bool in0 = xin && (yy >= 1) && (y0 <= 2047);
  // y1 = y0+1 interior: y1<=2047 -> yy<=1023; yt1 = y0 (even)
  const bool in1 = xin && has1 && (y0 + 1 <= 2047);
  const int row = (x >= 1) ? (((x - 1) & 1) ? 1024 + ((x - 1) >> 1) : ((x - 1) >> 1)) : 0;
  const int col0 = 1024 + yy - 1;                   // yt0 = 2yy-1 odd
  const int col1 = yy;                              // yt1 = 2yy even
  const size_t p0 = (size_t)x * 2049 + y0;

  float pm0[4], pm1[4];
#pragma unroll
  for (int m = 0; m < 4; ++m) {
    const size_t vb = (size_t)m * 4194304u + (size_t)row * 2048;
    const float i0 = in0 ? b2f(V[vb + col0]) : 0.f;
    const float i1 = in1 ? b2f(V[vb + col1]) : 0.f;
    const float alpha = -(sums[m] * (1.0f / 4194304.0f)) / hm[m];
    const size_t hb = (size_t)m * 4198401u + p0;
    pm0[m] = i0 + alpha * homsol[hb];
    pm1[m] = has1 ? (i1 + alpha * homsol[hb + 1]) : 0.f;
  }
#pragma unroll
  for (int l = 0; l < 4; ++l) {
    const float o0 = Cm2l[l * 4 + 0] * pm0[0] + Cm2l[l * 4 + 1] * pm0[1] +
                     Cm2l[l * 4 + 2] * pm0[2] + Cm2l[l * 4 + 3] * pm0[3];
    const size_t ob = (size_t)l * 4198401u + p0;
    if (has1) {
      const float o1 = Cm2l[l * 4 + 0] * pm1[0] + Cm2l[l * 4 + 1] * pm1[1] +
                       Cm2l[l * 4 + 2] * pm1[2] + Cm2l[l * 4 + 3] * pm1[3];
      float2v o; o[0] = o0; o[1] = o1;
      *(float2v*)&out[ob] = o;
    } else {
      out[ob] = o0;
    }
  }
}

extern "C" void kernel_launch(void* const* d_in, const int* in_sizes, int n_in,
                              void* d_out, int out_size, void* d_ws, size_t ws_size,
                              hipStream_t stream) {
  const float* q     = (const float*)d_in[0];   // [4,2047,2047]
  const float* Cl2m  = (const float*)d_in[1];   // [4,4]
  const float* Cm2l  = (const float*)d_in[2];   // [4,4]
  const float* H     = (const float*)d_in[3];   // [4,2047,2047]
  const float* hom   = (const float*)d_in[4];   // [4,2049,2049]
  const float* hmean = (const float*)d_in[5];   // [4]
  float* out = (float*)d_out;

  char* ws = (char*)d_ws;
  unsigned short* Tb = (unsigned short*)ws;                    //  8 MB: TE1|TO1|TE3|TO3
  unsigned short* Aslot = (unsigned short*)(ws + 8388608u);    // 32 MB: [E half | O half]
  unsigned short* Bslot = (unsigned short*)(ws + 41943040u);   // 32 MB
  float* sums        = (float*)(ws + 75497472u);               // 16 B
  unsigned short* AO = Aslot + 8388608u;                       // O-half base

  tables_kernel<<<4096, 256, 0, stream>>>(Tb);
  mix_fold<<<8192, 256, 0, stream>>>(q, Cl2m, Aslot, AO);
  hipMemsetAsync(sums, 0, 16, stream);

  const dim3 tg(32, 16, 4);
  // G1: Q1 = fold(P) x S  (DST along y)
  gemm_eo<0><<<256, 512, 0, stream>>>(Aslot, Tb, Bslot, nullptr, nullptr);
  // transpose + natural fold over x
  tfold<0><<<tg, 256, 0, stream>>>(Bslot, Aslot, AO);
  // G2: R = (fold(Q1^T) x S) / H  (DST along x; H computed in-epilogue)
  gemm_eo<1><<<256, 512, 0, stream>>>(Aslot, Tb, Bslot, H, nullptr);
  // interleaved column fold over spectral-x
  fold_cols<<<32768, 256, 0, stream>>>(Bslot, Aslot, AO);
  // G3: U = fold(R) x S  (inverse DST step 1) -- interleaved-fold tables
  gemm_eo<0><<<256, 512, 0, stream>>>(Aslot, Tb + 2097152u, Bslot, nullptr, nullptr);
  // transpose + interleaved fold over spectral-y
  tfold<1><<<tg, 256, 0, stream>>>(Bslot, Aslot, AO);
  // G4: V = fold(U^T) x S (+ per-mode sum)
  gemm_eo<2><<<256, 512, 0, stream>>>(Aslot, Tb + 2097152u, Bslot, nullptr, sums);

  final_kernel<<<8205, 256, 0, stream>>>(Bslot, hom, hmean, Cm2l, sums, out);
}